// Round 1
// baseline (2229.230 us; speedup 1.0000x reference)
//
#include <hip/hip_runtime.h>
#include <hip/hip_bf16.h>
#include <stdint.h>

#define B_ 2
#define L_ 2048
#define D_ 1024
#define FF_ 2048
#define V_ 32000
#define M_ (B_*L_)   // 4096 rows

typedef unsigned short u16;
typedef __attribute__((ext_vector_type(8))) short bf16x8;
typedef __attribute__((ext_vector_type(4))) float f32x4;

__device__ __forceinline__ u16 f2bf(float f) {
    unsigned u = __builtin_bit_cast(unsigned, f);
    unsigned r = (u + 0x7fffu + ((u >> 16) & 1u)) >> 16;
    return (u16)r;
}
__device__ __forceinline__ float bf2f(u16 h) {
    unsigned u = ((unsigned)h) << 16;
    return __builtin_bit_cast(float, u);
}
__device__ __forceinline__ float sigm(float x) { return 1.f / (1.f + __expf(-x)); }

__device__ __forceinline__ void async_copy16(const u16* g, u16* l) {
    __builtin_amdgcn_global_load_lds(
        (const __attribute__((address_space(1))) unsigned int*)g,
        (__attribute__((address_space(3))) unsigned int*)l, 16, 0, 0);
}

// ---------------- weight convert fp32 [K,N] -> bf16 transposed [N,K] ----------------
struct ConvDesc { const float* src; u16* dst; int K; int N; int tiles; int pad; };
struct ConvArgs { ConvDesc d[29]; int nmats; };

__global__ __launch_bounds__(256) void convert_kernel(ConvArgs args) {
    __shared__ float tile[64][65];
    int bid = blockIdx.x;
    int m = 0;
    while (m < args.nmats - 1 && bid >= args.d[m].tiles) { bid -= args.d[m].tiles; m++; }
    const float* src = args.d[m].src;
    u16* dst = args.d[m].dst;
    int K = args.d[m].K, N = args.d[m].N;
    int tn = N >> 6;
    int kt = bid / tn, nt = bid % tn;
    int k0 = kt * 64, n0 = nt * 64;
    int tx = threadIdx.x & 63, ty = threadIdx.x >> 6;
    for (int rr = 0; rr < 16; rr++) {
        int k = ty + rr * 4;
        tile[k][tx] = src[(size_t)(k0 + k) * N + n0 + tx];
    }
    __syncthreads();
    int tw = threadIdx.x & 31;      // k-pair index
    int tn2 = threadIdx.x >> 5;     // 0..7
    unsigned* dst32 = (unsigned*)dst;
    for (int pp = 0; pp < 8; pp++) {
        int n = tn2 + pp * 8;
        float f0 = tile[tw * 2][n], f1 = tile[tw * 2 + 1][n];
        unsigned pk = (unsigned)f2bf(f0) | ((unsigned)f2bf(f1) << 16);
        dst32[(((size_t)(n0 + n)) * K + k0) / 2 + tw] = pk;
    }
}

// ---------------- embedding gather + max_norm renorm ----------------
__global__ __launch_bounds__(256) void embed_kernel(const int* tokens, const float* emb, float* x) {
    int t = blockIdx.x;
    int tok = tokens[t];
    const float4* row = (const float4*)(emb + (size_t)tok * D_);
    int tid = threadIdx.x;
    float4 v = row[tid];
    float s = v.x * v.x + v.y * v.y + v.z * v.z + v.w * v.w;
    for (int o = 32; o > 0; o >>= 1) s += __shfl_down(s, o, 64);
    __shared__ float red[4];
    if ((tid & 63) == 0) red[tid >> 6] = s;
    __syncthreads();
    s = red[0] + red[1] + red[2] + red[3];
    float nrm = sqrtf(s);
    float sc = nrm > 1.f ? 1.f / (nrm + 1e-7f) : 1.f;
    float4 o4 = make_float4(v.x * sc, v.y * sc, v.z * sc, v.w * sc);
    ((float4*)(x + (size_t)t * D_))[tid] = o4;
}

// ---------------- rmsnorm fp32 row -> bf16 ----------------
__global__ __launch_bounds__(256) void rmsnorm_kernel(const float* x, const float* w, u16* xn) {
    int m = blockIdx.x, tid = threadIdx.x;
    float4 v = ((const float4*)(x + (size_t)m * D_))[tid];
    float s = v.x * v.x + v.y * v.y + v.z * v.z + v.w * v.w;
    for (int o = 32; o > 0; o >>= 1) s += __shfl_down(s, o, 64);
    __shared__ float red[4];
    if ((tid & 63) == 0) red[tid >> 6] = s;
    __syncthreads();
    s = red[0] + red[1] + red[2] + red[3];
    float r = rsqrtf(s * (1.f / D_) + 1e-6f);
    float4 wv = ((const float4*)w)[tid];
    ushort4 o;
    o.x = f2bf(v.x * r * wv.x);
    o.y = f2bf(v.y * r * wv.y);
    o.z = f2bf(v.z * r * wv.z);
    o.w = f2bf(v.w * r * wv.w);
    ((ushort4*)xn)[(size_t)m * (D_ / 4) + tid] = o;
}

// ---------------- GEMM: C[M,Ng] = A[M,K](bf16) * Bt[Ng,K]^T(bf16) + bias, fused epilogues ----------------
// op: 0 = fp32 store; 1 = sigmoid fp32; 2 = silu fp32; 3 = aux1 + v*aux2 fp32; 4 = aux1 + v fp32; 5 = bf16 store
struct GemmGroup {
    const u16* Bt; const float* bias;
    float* outF; u16* outB;
    const float* aux1; const float* aux2;
    int op; int Ng;
};
struct GemmArgs {
    GemmGroup g[3];
    const u16* A;
    int K; int ntPer; int Mtiles;
};

__global__ __launch_bounds__(256, 2) void gemm_kernel(GemmArgs args) {
    __shared__ __align__(16) u16 As[128 * 32];
    __shared__ __align__(16) u16 Bs[128 * 32];
    int tid = threadIdx.x, lane = tid & 63, wave = tid >> 6;
    int mt = blockIdx.x % args.Mtiles;
    int nt = blockIdx.x / args.Mtiles;
    int gidx = nt / args.ntPer, ntl = nt % args.ntPer;
    GemmGroup grp = args.g[gidx];
    int K = args.K;
    int m0 = mt * 128, n0 = ntl * 128;

    // staging: LDS chunk c (16B) holds tile row c>>2, global k-chunk (c&3)^((row>>1)&3)  (XOR swizzle)
    const u16* ag[2]; const u16* bg[2];
    u16* alds[2]; u16* blds[2];
#pragma unroll
    for (int r = 0; r < 2; r++) {
        int c = r * 256 + wave * 64 + lane;
        int row = c >> 2, q = c & 3;
        int col = (q ^ ((row >> 1) & 3)) * 8;
        ag[r] = args.A + (size_t)(m0 + row) * K + col;
        bg[r] = grp.Bt + (size_t)(n0 + row) * K + col;
        int cb = r * 256 + wave * 64;   // wave-uniform chunk base
        alds[r] = &As[cb * 8];
        blds[r] = &Bs[cb * 8];
    }

    int lm = lane & 15, q4 = lane >> 4;
    int wm = wave & 1, wn = wave >> 1;
    int aoff[4], boff[4];
#pragma unroll
    for (int i = 0; i < 4; i++) {
        int ra = wm * 64 + i * 16 + lm;
        aoff[i] = ra * 32 + ((q4 ^ ((ra >> 1) & 3)) * 8);
        int rb = wn * 64 + i * 16 + lm;
        boff[i] = rb * 32 + ((q4 ^ ((rb >> 1) & 3)) * 8);
    }

    f32x4 acc[4][4];
#pragma unroll
    for (int i = 0; i < 4; i++)
#pragma unroll
        for (int j = 0; j < 4; j++) {
            f32x4 z = {0.f, 0.f, 0.f, 0.f};
            acc[i][j] = z;
        }

    for (int k = 0; k < K; k += 32) {
        async_copy16(ag[0], alds[0]);
        async_copy16(ag[1], alds[1]);
        async_copy16(bg[0], blds[0]);
        async_copy16(bg[1], blds[1]);
        ag[0] += 32; ag[1] += 32; bg[0] += 32; bg[1] += 32;
        __syncthreads();   // drains vmcnt -> LDS data visible
        bf16x8 af[4], bfr[4];
#pragma unroll
        for (int i = 0; i < 4; i++) af[i]  = *(const bf16x8*)&As[aoff[i]];
#pragma unroll
        for (int i = 0; i < 4; i++) bfr[i] = *(const bf16x8*)&Bs[boff[i]];
#pragma unroll
        for (int i = 0; i < 4; i++)
#pragma unroll
            for (int j = 0; j < 4; j++)
                acc[i][j] = __builtin_amdgcn_mfma_f32_16x16x32_bf16(af[i], bfr[j], acc[i][j], 0, 0, 0);
        __syncthreads();   // protect LDS before next stage
    }

    int Ng = grp.Ng;
#pragma unroll
    for (int j = 0; j < 4; j++) {
        int col = n0 + wn * 64 + j * 16 + lm;
        float bcol = grp.bias[col];
#pragma unroll
        for (int i = 0; i < 4; i++) {
            int rbase = m0 + wm * 64 + i * 16 + q4 * 4;
            f32x4 v = acc[i][j];
#pragma unroll
            for (int rr = 0; rr < 4; rr++) {
                size_t idx = (size_t)(rbase + rr) * Ng + col;
                float val = v[rr] + bcol;
                switch (grp.op) {
                    case 0: grp.outF[idx] = val; break;
                    case 1: grp.outF[idx] = sigm(val); break;
                    case 2: grp.outF[idx] = val * sigm(val); break;
                    case 3: grp.outF[idx] = grp.aux1[idx] + val * grp.aux2[idx]; break;
                    case 4: grp.outF[idx] = grp.aux1[idx] + val; break;
                    case 5: grp.outB[idx] = f2bf(val); break;
                }
            }
        }
    }
}

// ---------------- chunked linear-recurrence scan: h = (1-a)*h + z*a ----------------
// 32 chunks of 64 along L. phase1: per-chunk (P = prod(1-a), S = chunk scan from 0).
// phase2: carry-in combined in-kernel, then recompute chunk emitting bf16 h.
__global__ __launch_bounds__(256) void scan_phase1(const float* zs, const float* as,
                                                   float* Ptab, float* Stab) {
    int bx = blockIdx.x;
    int b = bx >> 7, r = bx & 127, c = r >> 2, dblk = r & 3;
    int d = dblk * 256 + threadIdx.x;
    size_t base = ((size_t)(b * L_ + c * 64)) * D_ + d;
    float P = 1.f, S = 0.f;
#pragma unroll 8
    for (int l = 0; l < 64; l++) {
        float a = as[base], z = zs[base];
        base += D_;
        float om = 1.f - a;
        P *= om;
        S = om * S + z * a;
    }
    int ti = (b * 32 + c) * D_ + d;
    Ptab[ti] = P;
    Stab[ti] = S;
}

__global__ __launch_bounds__(256) void scan_phase2(const float* zs, const float* as,
                                                   const float* Ptab, const float* Stab,
                                                   const float* h0, u16* h) {
    int bx = blockIdx.x;
    int b = bx >> 7, r = bx & 127, c = r >> 2, dblk = r & 3;
    int d = dblk * 256 + threadIdx.x;
    float hv = h0[d];
    for (int j = 0; j < c; j++) {
        int ti = (b * 32 + j) * D_ + d;
        hv = Stab[ti] + Ptab[ti] * hv;
    }
    size_t base = ((size_t)(b * L_ + c * 64)) * D_ + d;
#pragma unroll 8
    for (int l = 0; l < 64; l++) {
        float a = as[base], z = zs[base];
        float om = 1.f - a;
        hv = om * hv + z * a;
        h[base] = f2bf(hv);
        base += D_;
    }
}

// ---------------- swiglu combine: g = f * silu(fa), bf16 ----------------
__global__ __launch_bounds__(256) void swiglu_kernel(const u16* f, const u16* fa, u16* gout) {
    int i = blockIdx.x * 256 + threadIdx.x;
    ushort4 fv = ((const ushort4*)f)[i];
    ushort4 av = ((const ushort4*)fa)[i];
    ushort4 o;
    float x0 = bf2f(fv.x), a0 = bf2f(av.x); o.x = f2bf(x0 * a0 * sigm(a0));
    float x1 = bf2f(fv.y), a1 = bf2f(av.y); o.y = f2bf(x1 * a1 * sigm(a1));
    float x2 = bf2f(fv.z), a2 = bf2f(av.z); o.z = f2bf(x2 * a2 * sigm(a2));
    float x3 = bf2f(fv.w), a3 = bf2f(av.w); o.w = f2bf(x3 * a3 * sigm(a3));
    ((ushort4*)gout)[i] = o;
}

extern "C" void kernel_launch(void* const* d_in, const int* in_sizes, int n_in,
                              void* d_out, int out_size, void* d_ws, size_t ws_size,
                              hipStream_t stream) {
    (void)in_sizes; (void)n_in; (void)out_size; (void)ws_size;
    const int*   tokens = (const int*)d_in[0];
    const float* emb    = (const float*)d_in[1];
    const float* W_ln_z = (const float*)d_in[2];
    const float* b_ln_z = (const float*)d_in[3];
    const float* W_dt   = (const float*)d_in[4];
    const float* b_dt   = (const float*)d_in[5];
    const float* W_y    = (const float*)d_in[6];
    const float* b_y    = (const float*)d_in[7];
    const float* W_ya   = (const float*)d_in[8];
    const float* b_ya   = (const float*)d_in[9];
    const float* h0     = (const float*)d_in[10];
    const float* Wf     = (const float*)d_in[11];
    const float* bf     = (const float*)d_in[12];
    const float* Wfa    = (const float*)d_in[13];
    const float* bfa    = (const float*)d_in[14];
    const float* Wo     = (const float*)d_in[15];
    const float* bo     = (const float*)d_in[16];
    const float* n1w    = (const float*)d_in[17];
    const float* n2w    = (const float*)d_in[18];
    const float* nlw    = (const float*)d_in[19];
    const float* W_out  = (const float*)d_in[20];
    const float* b_out  = (const float*)d_in[21];
    float* out = (float*)d_out;

    char* ws = (char*)d_ws;
    size_t off = 0;
    auto alloc = [&](size_t bytes) -> void* {
        void* p = ws + off;
        off += (bytes + 255) & ~(size_t)255;
        return p;
    };

    u16 *wz[4], *wdt[4], *wya[4], *wy[4], *wfp[4], *wfap[4], *wop[4];
    for (int i = 0; i < 4; i++) {
        wz[i]   = (u16*)alloc((size_t)1024 * 1024 * 2);
        wdt[i]  = (u16*)alloc((size_t)1024 * 1024 * 2);
        wya[i]  = (u16*)alloc((size_t)1024 * 1024 * 2);
        wy[i]   = (u16*)alloc((size_t)1024 * 1024 * 2);
        wfp[i]  = (u16*)alloc((size_t)1024 * 2048 * 2);
        wfap[i] = (u16*)alloc((size_t)1024 * 2048 * 2);
        wop[i]  = (u16*)alloc((size_t)2048 * 1024 * 2);
    }
    u16* wout = (u16*)alloc((size_t)1024 * 32000 * 2);
    float* x  = (float*)alloc((size_t)M_ * D_ * 4);
    u16* xn   = (u16*)alloc((size_t)M_ * D_ * 2);
    float* Ptab = (float*)alloc((size_t)2 * 32 * 1024 * 4);
    float* Stab = (float*)alloc((size_t)2 * 32 * 1024 * 4);
    // scratch pool shared between sioconv (zs/as/sya fp32 + h bf16) and ffn (f/fa/g bf16)
    char* pool = (char*)alloc((size_t)3 * M_ * D_ * 4 + (size_t)M_ * D_ * 2);
    float* zs  = (float*)pool;
    float* as_ = zs + (size_t)M_ * D_;
    float* sya = as_ + (size_t)M_ * D_;
    u16* h     = (u16*)(sya + (size_t)M_ * D_);
    u16* f     = (u16*)pool;
    u16* fa    = f + (size_t)M_ * FF_;
    u16* g     = fa + (size_t)M_ * FF_;

    // ---- weight conversion (one launch, all 29 matrices) ----
    ConvArgs ca;
    int nm = 0, totTiles = 0;
    auto addm = [&](const float* s, u16* d, int K, int N) {
        ca.d[nm].src = s; ca.d[nm].dst = d; ca.d[nm].K = K; ca.d[nm].N = N;
        ca.d[nm].tiles = (K >> 6) * (N >> 6); ca.d[nm].pad = 0;
        totTiles += ca.d[nm].tiles; nm++;
    };
    for (int i = 0; i < 4; i++) {
        addm(W_ln_z + (size_t)i * 1024 * 1024, wz[i], 1024, 1024);
        addm(W_dt   + (size_t)i * 1024 * 1024, wdt[i], 1024, 1024);
        addm(W_ya   + (size_t)i * 1024 * 1024, wya[i], 1024, 1024);
        addm(W_y    + (size_t)i * 1024 * 1024, wy[i], 1024, 1024);
        addm(Wf     + (size_t)i * 1024 * 2048, wfp[i], 1024, 2048);
        addm(Wfa    + (size_t)i * 1024 * 2048, wfap[i], 1024, 2048);
        addm(Wo     + (size_t)i * 2048 * 1024, wop[i], 2048, 1024);
    }
    addm(W_out, wout, 1024, 32000);
    ca.nmats = nm;
    convert_kernel<<<totTiles, 256, 0, stream>>>(ca);

    embed_kernel<<<M_, 256, 0, stream>>>(tokens, emb, x);

    for (int i = 0; i < 4; i++) {
        rmsnorm_kernel<<<M_, 256, 0, stream>>>(x, n1w + i * 1024, xn);

        GemmArgs gaA{};
        gaA.A = xn; gaA.K = 1024; gaA.ntPer = 8; gaA.Mtiles = 32;
        gaA.g[0] = {wz[i],  b_ln_z + i * 1024, zs,  nullptr, nullptr, nullptr, 1, 1024};
        gaA.g[1] = {wdt[i], b_dt   + i * 1024, as_, nullptr, nullptr, nullptr, 1, 1024};
        gaA.g[2] = {wya[i], b_ya   + i * 1024, sya, nullptr, nullptr, nullptr, 2, 1024};
        gemm_kernel<<<32 * 24, 256, 0, stream>>>(gaA);

        scan_phase1<<<256, 256, 0, stream>>>(zs, as_, Ptab, Stab);
        scan_phase2<<<256, 256, 0, stream>>>(zs, as_, Ptab, Stab, h0 + i * 1024, h);

        GemmArgs gaB{};
        gaB.A = h; gaB.K = 1024; gaB.ntPer = 8; gaB.Mtiles = 32;
        gaB.g[0] = {wy[i], b_y + i * 1024, x, nullptr, x, sya, 3, 1024};
        gemm_kernel<<<32 * 8, 256, 0, stream>>>(gaB);

        rmsnorm_kernel<<<M_, 256, 0, stream>>>(x, n2w + i * 1024, xn);

        GemmArgs gaC{};
        gaC.A = xn; gaC.K = 1024; gaC.ntPer = 16; gaC.Mtiles = 32;
        gaC.g[0] = {wfp[i],  bf  + i * 2048, nullptr, f,  nullptr, nullptr, 5, 2048};
        gaC.g[1] = {wfap[i], bfa + i * 2048, nullptr, fa, nullptr, nullptr, 5, 2048};
        gemm_kernel<<<32 * 32, 256, 0, stream>>>(gaC);

        swiglu_kernel<<<(M_ * FF_ / 4) / 256, 256, 0, stream>>>(f, fa, g);

        GemmArgs gaD{};
        gaD.A = g; gaD.K = 2048; gaD.ntPer = 8; gaD.Mtiles = 32;
        gaD.g[0] = {wop[i], bo + i * 1024, x, nullptr, x, nullptr, 4, 1024};
        gemm_kernel<<<32 * 8, 256, 0, stream>>>(gaD);
    }

    rmsnorm_kernel<<<M_, 256, 0, stream>>>(x, nlw, xn);

    GemmArgs gaF{};
    gaF.A = xn; gaF.K = 1024; gaF.ntPer = 250; gaF.Mtiles = 32;
    gaF.g[0] = {wout, b_out, out, nullptr, nullptr, nullptr, 0, 32000};
    gemm_kernel<<<32 * 250, 256, 0, stream>>>(gaF);
}